// Round 1
// 215.199 us; speedup vs baseline: 1.0874x; 1.0874x over previous
//
#include <hip/hip_runtime.h>

#define KC 1024   // codes
#define DD 128    // dim
#define NT_COUNT (KC / 16)   // 64 code-tiles of 16
#define RPB 64    // rows per block (one wave, 4 m-tiles)

typedef short bf16x8 __attribute__((ext_vector_type(8)));
typedef float f32x4  __attribute__((ext_vector_type(4)));

#define AS1 __attribute__((address_space(1)))
#define AS3 __attribute__((address_space(3)))

static __device__ __forceinline__ unsigned short f2bf(float f) {
    unsigned u = __float_as_uint(f);
    unsigned r = (u + 0x7fffu + ((u >> 16) & 1u)) >> 16;   // RNE
    return (unsigned short)r;
}
static __device__ __forceinline__ float bf2f(unsigned short h) {
    return __uint_as_float(((unsigned)h) << 16);
}
static __device__ __forceinline__ void gl_lds16(const void* g, void* l) {
    __builtin_amdgcn_global_load_lds((const AS1 void*)g, (AS3 void*)l, 16, 0, 0);
}
static __device__ __forceinline__ void gl_lds4(const void* g, void* l) {
    __builtin_amdgcn_global_load_lds((const AS1 void*)g, (AS3 void*)l, 4, 0, 0);
}

// ---------------- fused prep: e2h (+512 offset) + ET + packed bf16 hi/lo B-fragments ----------------
// Bpk byte layout: [nt][c(8)x1024][lane(64)x16]; c<4 = hi s=c, c>=4 = lo s=c-4.
//   element (d,k): d = s*32 + (lane>>4)*8 + j ; k = nt*16 + (lane&15)
__global__ __launch_bounds__(256) void vq_prep(const float* __restrict__ E,
                                               float* __restrict__ e2h,
                                               float* __restrict__ ET,
                                               unsigned short* __restrict__ Bpk) {
    __shared__ float T[16 * 129];   // [k][d]
    const int nt  = blockIdx.x;     // 64 blocks, 16 codes each
    const int tid = threadIdx.x;

    for (int i = tid; i < 16 * DD; i += 256) {
        int d  = i >> 4;
        int kk = i & 15;
        T[kk * 129 + d] = E[(size_t)d * KC + nt * 16 + kk];
    }
    __syncthreads();

    // e2h = 512 - 0.5*||e_k||^2 (offset keeps all screen scores positive)
    if (tid < 16) {
        float s = 0.f;
#pragma unroll 16
        for (int d = 0; d < DD; ++d) {
            float v = T[tid * 129 + d];
            s = fmaf(v, v, s);
        }
        e2h[nt * 16 + tid] = 512.0f - 0.5f * s;
    }

    for (int i = tid; i < 16 * DD; i += 256) {
        int kk = i >> 7;
        int d  = i & 127;
        ET[(size_t)(nt * 16 + kk) * DD + d] = T[kk * 129 + d];
    }

    {
        const int s    = tid >> 6;
        const int lane = tid & 63;
        const int kk   = lane & 15;
        const int d0   = s * 32 + (lane >> 4) * 8;
        bf16x8 hi, lo;
#pragma unroll
        for (int j = 0; j < 8; ++j) {
            float v = T[kk * 129 + d0 + j];
            unsigned short h = f2bf(v);
            hi[j] = (short)h;
            lo[j] = (short)f2bf(v - bf2f(h));
        }
        char* base = (char*)Bpk + (size_t)nt * 8192 + s * 1024 + lane * 16;
        *(bf16x8*)(base)        = hi;
        *(bf16x8*)(base + 4096) = lo;
    }
}

// ---------------- main: single-wave, 64 rows/wave, LDS dbuf via global_load_lds + vmcnt ----------------
// LDS: two buffers, stride 8448: [c(8)x1024 frags][e2 256B]. Epilogue reuses dead buf0 head.
__global__ __launch_bounds__(64, 2) void vq_main(const float* __restrict__ X,
                                                 const float* __restrict__ e2h,
                                                 const float* __restrict__ ET,
                                                 const unsigned short* __restrict__ Bpk,
                                                 float* __restrict__ Out) {
    __shared__ __align__(16) char lds[2 * 8448];
    int*   s_k1  = (int*)(lds);          // [64]
    int*   s_k2  = (int*)(lds + 256);    // [64]
    int*   s_win = (int*)(lds + 512);    // [64]
    float* s_gap = (float*)(lds + 768);  // [64] screen top1-top2 margin

    const int lane  = threadIdx.x;   // single wave
    const int quad  = lane >> 4;
    const int n16   = lane & 15;
    const int wrow0 = blockIdx.x * RPB;
    const int lidx16 = lane * 16;
    const int lidx4  = lane * 4;

    // ---- A-fragments: 4 m-tiles x 4 k-steps, hi+lo (128 VGPRs)
    bf16x8 ahi[4][4], alo[4][4];
#pragma unroll
    for (int t = 0; t < 4; ++t) {
#pragma unroll
        for (int s = 0; s < 4; ++s) {
            const int row = wrow0 + t * 16 + n16;
            const int d0  = s * 32 + quad * 8;
            const float4 p = *(const float4*)(X + (size_t)row * DD + d0);
            const float4 q = *(const float4*)(X + (size_t)row * DD + d0 + 4);
            float v[8] = {p.x, p.y, p.z, p.w, q.x, q.y, q.z, q.w};
#pragma unroll
            for (int j = 0; j < 8; ++j) {
                unsigned short h = f2bf(v[j]);
                ahi[t][s][j] = (short)h;
                alo[t][s][j] = (short)f2bf(v[j] - bf2f(h));
            }
        }
    }

    // ---- top-2 trackers: positive floats with 6-bit tile id in low mantissa bits
    float p1[4][4], p2[4][4];
#pragma unroll
    for (int t = 0; t < 4; ++t)
#pragma unroll
        for (int r = 0; r < 4; ++r) { p1[t][r] = 0.0f; p2[t][r] = 0.0f; }

#define STAGE(NT, BOFF)                                                          \
    do {                                                                         \
        const char* g = (const char*)Bpk + (size_t)(NT) * 8192;                  \
        _Pragma("unroll")                                                        \
        for (int c = 0; c < 8; ++c)                                              \
            gl_lds16(g + c * 1024 + lidx16, lds + (BOFF) + c * 1024);            \
        gl_lds4(e2h + (NT) * 16 + n16, lds + (BOFF) + 8192);                     \
    } while (0)

#define TILE(NT, BOFF)                                                           \
    do {                                                                         \
        const char* l = lds + (BOFF);                                            \
        const bf16x8 bh0 = *(const bf16x8*)(l + 0 * 1024 + lidx16);              \
        const bf16x8 bh1 = *(const bf16x8*)(l + 1 * 1024 + lidx16);              \
        const bf16x8 bh2 = *(const bf16x8*)(l + 2 * 1024 + lidx16);              \
        const bf16x8 bh3 = *(const bf16x8*)(l + 3 * 1024 + lidx16);              \
        const bf16x8 bl0 = *(const bf16x8*)(l + 4 * 1024 + lidx16);              \
        const bf16x8 bl1 = *(const bf16x8*)(l + 5 * 1024 + lidx16);              \
        const bf16x8 bl2 = *(const bf16x8*)(l + 6 * 1024 + lidx16);              \
        const bf16x8 bl3 = *(const bf16x8*)(l + 7 * 1024 + lidx16);              \
        const float  ev  = *(const float*)(l + 8192 + lidx4);                    \
        const unsigned ntinv = (unsigned)(63 - (NT));                            \
        _Pragma("unroll")                                                        \
        for (int t = 0; t < 4; ++t) {                                            \
            f32x4 acc = {ev, ev, ev, ev};                                        \
            acc = __builtin_amdgcn_mfma_f32_16x16x32_bf16(ahi[t][0], bh0, acc, 0, 0, 0); \
            acc = __builtin_amdgcn_mfma_f32_16x16x32_bf16(ahi[t][1], bh1, acc, 0, 0, 0); \
            acc = __builtin_amdgcn_mfma_f32_16x16x32_bf16(ahi[t][2], bh2, acc, 0, 0, 0); \
            acc = __builtin_amdgcn_mfma_f32_16x16x32_bf16(ahi[t][3], bh3, acc, 0, 0, 0); \
            acc = __builtin_amdgcn_mfma_f32_16x16x32_bf16(alo[t][0], bh0, acc, 0, 0, 0); \
            acc = __builtin_amdgcn_mfma_f32_16x16x32_bf16(alo[t][1], bh1, acc, 0, 0, 0); \
            acc = __builtin_amdgcn_mfma_f32_16x16x32_bf16(alo[t][2], bh2, acc, 0, 0, 0); \
            acc = __builtin_amdgcn_mfma_f32_16x16x32_bf16(alo[t][3], bh3, acc, 0, 0, 0); \
            acc = __builtin_amdgcn_mfma_f32_16x16x32_bf16(ahi[t][0], bl0, acc, 0, 0, 0); \
            acc = __builtin_amdgcn_mfma_f32_16x16x32_bf16(ahi[t][1], bl1, acc, 0, 0, 0); \
            acc = __builtin_amdgcn_mfma_f32_16x16x32_bf16(ahi[t][2], bl2, acc, 0, 0, 0); \
            acc = __builtin_amdgcn_mfma_f32_16x16x32_bf16(ahi[t][3], bl3, acc, 0, 0, 0); \
            _Pragma("unroll")                                                    \
            for (int r = 0; r < 4; ++r) {                                        \
                float v = __uint_as_float((__float_as_uint(acc[r]) & ~63u) | ntinv); \
                float lo = fminf(p1[t][r], v);                                   \
                p1[t][r] = fmaxf(p1[t][r], v);                                   \
                p2[t][r] = fmaxf(p2[t][r], lo);                                  \
            }                                                                    \
        }                                                                        \
    } while (0)

    STAGE(0, 0);
    for (int nt = 0; nt < NT_COUNT; nt += 2) {
        // half A: tile nt in buf0
        STAGE(nt + 1, 8448);
        __builtin_amdgcn_s_waitcnt(3961);       // vmcnt(9): tile nt's 9 complete
        __builtin_amdgcn_sched_barrier(0);
        TILE(nt, 0);
        // half B: tile nt+1 in buf1
        if (nt + 2 < NT_COUNT) {
            STAGE(nt + 2, 0);
            __builtin_amdgcn_s_waitcnt(3961);   // vmcnt(9): tile nt+1's 9 complete
        } else {
            __builtin_amdgcn_s_waitcnt(3952);   // vmcnt(0)
        }
        __builtin_amdgcn_sched_barrier(0);
        TILE(nt + 1, 8448);
    }
#undef STAGE
#undef TILE

    // ---- re-attach full k, merge top-2 across the 16 n-lanes (u64 butterfly)
#pragma unroll
    for (int t = 0; t < 4; ++t) {
#pragma unroll
        for (int r = 0; r < 4; ++r) {
            unsigned u1 = __float_as_uint(p1[t][r]);
            unsigned u2 = __float_as_uint(p2[t][r]);
            int k1 = (int)(63u - (u1 & 63u)) * 16 + n16;
            int k2 = (int)(63u - (u2 & 63u)) * 16 + n16;
            unsigned long long q1 =
                ((unsigned long long)(u1 & ~63u) << 32) | (unsigned)(1023 - k1);
            unsigned long long q2 =
                ((unsigned long long)(u2 & ~63u) << 32) | (unsigned)(1023 - k2);
#pragma unroll
            for (int m = 1; m < 16; m <<= 1) {
                unsigned long long o1 = __shfl_xor(q1, m, 64);
                unsigned long long o2 = __shfl_xor(q2, m, 64);
                unsigned long long lo = q1 < o1 ? q1 : o1;
                q1 = q1 > o1 ? q1 : o1;
                unsigned long long hi2 = q2 > o2 ? q2 : o2;
                q2 = lo > hi2 ? lo : hi2;
            }
            if (n16 == 0) {
                int row = t * 16 + quad * 4 + r;
                s_k1[row] = 1023 - (int)(q1 & 1023u);
                s_k2[row] = 1023 - (int)(q2 & 1023u);
                // screen margin (id bits already cleared in both high words)
                s_gap[row] = __uint_as_float((unsigned)(q1 >> 32)) -
                             __uint_as_float((unsigned)(q2 >> 32));
            }
        }
    }
    __syncthreads();

    // ---- fp64 rescore: ONLY for rows whose screen margin is within the error
    // bound of the bf16 hi/lo screen. Worst-case screen error vs exact distance
    // is ~0.06 (lo*lo omission 0.018 + lo double-rounding 0.036 + fp32 accum
    // 0.003 + id-mask 0.008); THR=0.5 gives an 8x margin, so gap >= THR proves
    // k1 is the exact argmin. Typical gaps are ~4-5, so ~90% of lanes skip the
    // (fully divergent) gather entirely.
    {
        const int k1 = s_k1[lane];
        const int k2 = s_k2[lane];
        int win = k1;
        if (s_gap[lane] < 0.5f) {
            const float4* __restrict__ xr  = (const float4*)(X + (size_t)(wrow0 + lane) * DD);
            const float4* __restrict__ e1  = (const float4*)(ET + (size_t)k1 * DD);
            const float4* __restrict__ e2p = (const float4*)(ET + (size_t)k2 * DD);
            double dot1 = 0.0, ee1 = 0.0, dot2 = 0.0, ee2 = 0.0;
#pragma unroll 4
            for (int d4 = 0; d4 < DD / 4; ++d4) {
                const float4 xv = xr[d4];
                const float4 v1 = e1[d4];
                const float4 v2 = e2p[d4];
                const float xs[4] = {xv.x, xv.y, xv.z, xv.w};
                const float a1[4] = {v1.x, v1.y, v1.z, v1.w};
                const float a2[4] = {v2.x, v2.y, v2.z, v2.w};
#pragma unroll
                for (int j = 0; j < 4; ++j) {   // same accumulation order as before
                    const double xd  = (double)xs[j];
                    const double v1d = (double)a1[j];
                    const double v2d = (double)a2[j];
                    dot1 = fma(xd, v1d, dot1);
                    ee1  = fma(v1d, v1d, ee1);
                    dot2 = fma(xd, v2d, dot2);
                    ee2  = fma(v2d, v2d, ee2);
                }
            }
            double d1 = ee1 - 2.0 * dot1;
            double d2 = ee2 - 2.0 * dot2;
            win = (d2 < d1 || (d2 == d1 && k2 < k1)) ? k2 : k1;
        }
        s_win[lane] = win;
    }
    __syncthreads();

    // ---- gather winning code rows (exact fp32 copies), coalesced float4
    for (int i = lane; i < RPB * (DD / 4); i += 64) {
        const int row = i >> 5;
        const int d4  = i & 31;
        const float4 v = *(const float4*)(ET + (size_t)s_win[row] * DD + d4 * 4);
        *(float4*)(Out + (size_t)(wrow0 + row) * DD + d4 * 4) = v;
    }
}

extern "C" void kernel_launch(void* const* d_in, const int* in_sizes, int n_in,
                              void* d_out, int out_size, void* d_ws, size_t ws_size,
                              hipStream_t stream) {
    const float* X = (const float*)d_in[0];   // [131072, 128]
    const float* E = (const float*)d_in[1];   // [128, 1024]
    float* Out = (float*)d_out;

    // workspace: e2h (4 KB) | ET (512 KB) | Bpk (512 KB)
    float* e2h = (float*)d_ws;
    float* ET  = e2h + KC;
    unsigned short* Bpk = (unsigned short*)(ET + (size_t)KC * DD);

    const int N = in_sizes[0] / DD;   // 131072

    hipLaunchKernelGGL(vq_prep, dim3(NT_COUNT), dim3(256), 0, stream, E, e2h, ET, Bpk);
    hipLaunchKernelGGL(vq_main, dim3(N / RPB), dim3(64), 0, stream,
                       X, e2h, ET, Bpk, Out);
}